// Round 11
// baseline (3126.903 us; speedup 1.0000x reference)
//
#include <hip/hip_runtime.h>
#include <math.h>

typedef unsigned short u16;
typedef unsigned long long u64t;
typedef __bf16 bf16x8 __attribute__((ext_vector_type(8)));
typedef float f32x4 __attribute__((ext_vector_type(4)));
struct alignas(8) u16x4 { u16 x0, x1, x2, x3; };

__device__ __forceinline__ int ufl(int v) { return __builtin_amdgcn_readfirstlane(v); }
__device__ __forceinline__ u16 f2b(float f) {
    unsigned u = __float_as_uint(f);
    return (u16)((u + 0x7FFFu + ((u >> 16) & 1u)) >> 16);   // RNE fp32->bf16
}
__device__ __forceinline__ float b2f(u16 h) { return __uint_as_float(((unsigned)h) << 16); }
__device__ __forceinline__ u16 tob(float v) { return f2b(v); }
__device__ __forceinline__ u16 tob(u16 v)   { return v; }

// ---------------------------------------------------------------------------
// SESSION LEDGER (counter evidence):
//  * r0-r2: WRITE_SIZE 66x amp was scratch SPILL (acc[64] @ VGPR 64), not
//    store width. Fix confirmed r4. ALWAYS check VGPR vs per-thread arrays.
//  * r3 lesson: u64 = FOUR u16. Verify copy-loop element counts.
//  * r4->r5: GDN moved to MFMA (gdnm). 5597->3808.
//  * r5->r7: mconv af reg-double-buffer (dist-1): 3808->3466, MfmaUtil
//    15.6->22.3% (predicted 30-35 -> only half; dist-1 = 78cy hide vs
//    ~200cy L2 latency, lockstep waves don't interleave stalls).
//  * r7->r8: trik -> MFMA GEMM form (trik_m + rk_inv): 3466->3036.
//  * r8: prefetch distance 2 (4-buffer P/Q ping-pong, loads issued ~156cy
//    before use) for mconv MT<=4 and mdeconv2. MT=5 keeps dist-1 path.
//  * r9/r10: bench infra failures (container acquisition), kernel never ran.
//    Resubmitted unchanged (r8 baseline of this source: 3036us, passing).
// ---------------------------------------------------------------------------

// ---------------------------------------------------------------------------
// Weight repacks (paired u32 stores).
// ---------------------------------------------------------------------------
// forward conv: W[COUT][CIN][25] f32 -> A[25][COUT][CIN] bf16 (ci pairs)
template<int CIN, int COUT>
__global__ __launch_bounds__(256) void rk_fwd(const float* __restrict__ w, u16* __restrict__ a) {
    int j = (blockIdx.x * 256 + threadIdx.x) * 2;
    if (j >= 25 * COUT * CIN) return;
    int ci = j % CIN; int r = j / CIN; int co = r % COUT; int t = r / COUT;
    u16 lo = f2b(w[(co * CIN + ci) * 25 + t]);
    u16 hi = f2b(w[(co * CIN + ci + 1) * 25 + t]);
    *(unsigned*)&a[j] = (unsigned)lo | ((unsigned)hi << 16);
}
// deconv1 (s1 gather): W[320ci][256co][25] -> A[t'][256co][320ci], t'=(4-ky)*5+(4-kx)
__global__ __launch_bounds__(256) void rk_d1(const float* __restrict__ w, u16* __restrict__ a) {
    int j = (blockIdx.x * 256 + threadIdx.x) * 2;
    if (j >= 25 * 256 * 320) return;
    int ci = j % 320; int r = j / 320; int co = r % 256; int tp = r / 256;
    int ky = 4 - tp / 5, kx = 4 - tp % 5;
    u16 lo = f2b(w[(ci * 256 + co) * 25 + ky * 5 + kx]);
    u16 hi = f2b(w[((ci + 1) * 256 + co) * 25 + ky * 5 + kx]);
    *(unsigned*)&a[j] = (unsigned)lo | ((unsigned)hi << 16);
}
// deconv2 (s2 parity): W[256ci][256co][25] -> A2[q*9+tt][256co][256ci], zero invalid taps
__global__ __launch_bounds__(256) void rk_d2(const float* __restrict__ w, u16* __restrict__ a) {
    int j = (blockIdx.x * 256 + threadIdx.x) * 2;
    if (j >= 36 * 256 * 256) return;
    int ci = j % 256; int r = j / 256; int co = r % 256; int qt = r / 256;
    int q = qt / 9, tt = qt % 9;
    int qy = q >> 1, qx = q & 1, ty = tt / 3, tx = tt % 3;
    u16 lo = 0, hi = 0;
    if (ty < 3 - qy && tx < 3 - qx) {
        int widx = (qy + 2 * ty) * 5 + (qx + 2 * tx);
        lo = f2b(w[(ci * 256 + co) * 25 + widx]);
        hi = f2b(w[((ci + 1) * 256 + co) * 25 + widx]);
    }
    *(unsigned*)&a[j] = (unsigned)lo | ((unsigned)hi << 16);
}
// deconv3: W[256ci][2co][25] f32 -> W3r[4q][256ci][2co][16] f32 (9 taps zero-padded)
__global__ __launch_bounds__(256) void rk_d3(const float* __restrict__ w, float* __restrict__ a) {
    int i = blockIdx.x * 256 + threadIdx.x;
    if (i >= 4 * 256 * 2 * 16) return;
    int t = i % 16; int r = i / 16; int co = r % 2; int r2 = r / 2; int ci = r2 % 256; int q = r2 / 256;
    int qy = q >> 1, qx = q & 1;
    float v = 0.f;
    if (t < 9) {
        int ty = t / 3, tx = t % 3;
        if (ty < 3 - qy && tx < 3 - qx) v = w[(ci * 2 + co) * 25 + (qy + 2 * ty) * 5 + (qx + 2 * tx)];
    }
    a[i] = v;
}
// GDN gamma: f32 [256co][256ci] -> bf16 [co][ci] (ci pairs)
__global__ __launch_bounds__(256) void rk_g(const float* __restrict__ g, u16* __restrict__ a) {
    int j = (blockIdx.x * 256 + threadIdx.x) * 2;
    if (j >= 256 * 256) return;
    u16 lo = f2b(g[j]);
    u16 hi = f2b(g[j + 1]);
    *(unsigned*)&a[j] = (unsigned)lo | ((unsigned)hi << 16);
}
// context H: f32 [320c][64i][64j] -> bf16 strictly-lower-masked, row-major
__global__ __launch_bounds__(256) void rk_hb(const float* __restrict__ H, u16* __restrict__ a) {
    int p = blockIdx.x * 256 + threadIdx.x;   // pair index
    if (p >= 320 * 2048) return;
    int j2 = (p & 31) * 2;
    int r = p >> 5;                           // c*64 + i
    int i = r & 63;
    u16 lo = (j2 < i) ? f2b(H[(size_t)r * 64 + j2]) : (u16)0;
    u16 hi = (j2 + 1 < i) ? f2b(H[(size_t)r * 64 + j2 + 1]) : (u16)0;
    *(unsigned*)&a[(size_t)r * 64 + j2] = (unsigned)lo | ((unsigned)hi << 16);
}
// context inverse: Mb[c] = ((I - H_tril)^{-1} - I) strictly lower, bf16.
__global__ __launch_bounds__(256)
void rk_inv(const float* __restrict__ H, u16* __restrict__ Mb)
{
    __shared__ float Ls[64 * 68];
    __shared__ float Ms[64 * 68];
    const int c = blockIdx.x, tid = threadIdx.x;
    const float* Hc = H + (size_t)c * 4096;
#pragma unroll
    for (int it = 0; it < 16; ++it) {
        int v = it * 256 + tid;               // [0,4096)
        int i = v >> 6, j = v & 63;
        Ls[i * 68 + j] = (j < i) ? Hc[v] : 0.f;
    }
    __syncthreads();
    if (tid < 64) {
        const int j = tid;
#pragma unroll 1
        for (int i = 0; i < 64; ++i) {
            float s = (i == j) ? 1.f : 0.f;
#pragma unroll 1
            for (int k = 0; k < i; ++k)
                s = fmaf(Ls[i * 68 + k], Ms[k * 68 + j], s);
            Ms[i * 68 + j] = s;
        }
    }
    __syncthreads();
#pragma unroll
    for (int it = 0; it < 8; ++it) {
        int p = it * 256 + tid;               // [0,2048) pairs
        int i = p >> 5, j2 = (p & 31) * 2;
        u16 lo = (j2 < i) ? f2b(Ms[i * 68 + j2]) : (u16)0;
        u16 hi = (j2 + 1 < i) ? f2b(Ms[i * 68 + j2 + 1]) : (u16)0;
        *(unsigned*)&Mb[(size_t)c * 4096 + i * 64 + j2] = (unsigned)lo | ((unsigned)hi << 16);
    }
}

// ---------------------------------------------------------------------------
// MFMA implicit-GEMM conv (k=5 pad=2 stride S in {1,2}), out 8x8 per image.
// MT<=4: prefetch DISTANCE 2 (P/Q 4-buffer ping-pong, A-loads issued ~2 MFMA
// blocks before use). MT==5: distance-1 2-buffer path (VGPR budget).
// TOUT=float: dword stores. TOUT=u16: LDS-bounce epilogue -> u64 stores.
// ---------------------------------------------------------------------------
#define MC_LD(DST, I) do {                                                     \
    const int _tp = (I) >> 1, _kk = (I) & 1;                                   \
    const size_t _oo = (size_t)_tp * (COUT * CIN) + _kk * 32;                  \
    _Pragma("unroll")                                                          \
    for (int _m = 0; _m < MT; ++_m) DST[_m] = *(const bf16x8*)(Ar[_m] + _oo);  \
} while (0)

#define MC_FMA(SRC, I) do {                                                    \
    const int _tp = (I) >> 1, _kk = (I) & 1;                                   \
    const int _tofs = ((_tp / 5) * HP + (_tp % 5)) * STRIDE + _kk * 32;        \
    bf16x8 _bf[4];                                                             \
    _Pragma("unroll")                                                          \
    for (int _nt = 0; _nt < 4; ++_nt)                                          \
        _bf[_nt] = *(const bf16x8*)&bs[bofs[_nt] + _tofs];                     \
    _Pragma("unroll")                                                          \
    for (int _m = 0; _m < MT; ++_m)                                            \
        _Pragma("unroll")                                                      \
        for (int _nt = 0; _nt < 4; ++_nt)                                      \
            acc[_m][_nt] = __builtin_amdgcn_mfma_f32_16x16x32_bf16(            \
                SRC[_m], _bf[_nt], acc[_m][_nt], 0, 0, 0);                     \
} while (0)

template<int CIN, int COUT, int S, int MT, typename TIN, typename TOUT>
__global__ __launch_bounds__(256)
void mconv(const TIN* __restrict__ in, const u16* __restrict__ A,
           const float* __restrict__ bias, TOUT* __restrict__ out)
{
    constexpr bool O16 = (sizeof(TOUT) == 2);
    constexpr int HIN = 8 * S, HP = 7 * S + 5, CHUNK = 64, STRIDE = CHUNK + 8;
    constexpr int NCH = CIN / CHUNK;
    constexpr int SP = HP * HP;
    constexpr int BSE = SP * STRIDE;
    constexpr int OSE = O16 ? COUT * 64 : 0;
    constexpr int NIT = 50;                    // 25 taps * 2 kc; NIT%4==2
    __shared__ u16 bs[(BSE > OSE) ? BSE : OSE];

    const int b = blockIdx.x;
    const int tid = threadIdx.x;
    const int lane = tid & 63, wv = tid >> 6;
    const int lm = lane & 15, quad = lane >> 4;
    const int cob = wv * (MT * 16);
    const TIN* inb = in + (size_t)b * CIN * (HIN * HIN);

    int bofs[4];
#pragma unroll
    for (int nt = 0; nt < 4; ++nt) {
        int px = nt * 16 + lm, oy = px >> 3, ox = px & 7;
        bofs[nt] = (S * oy * HP + S * ox) * STRIDE + quad * 8;
    }

    f32x4 acc[MT][4];
#pragma unroll
    for (int m = 0; m < MT; ++m)
#pragma unroll
        for (int n = 0; n < 4; ++n) acc[m][n] = (f32x4){0.f, 0.f, 0.f, 0.f};

#pragma unroll 1
    for (int ch = 0; ch < NCH; ++ch) {
        if (ch) __syncthreads();
        unsigned* bz = (unsigned*)bs;
        for (int i = tid; i < BSE / 2; i += 256) bz[i] = 0u;
        __syncthreads();
        for (int i = tid; i < (CHUNK / 4) * (HIN * HIN); i += 256) {
            int px = i % (HIN * HIN), cg = i / (HIN * HIN);
            int iy = px / HIN, ix = px % HIN;
            const TIN* ip = inb + (size_t)(ch * CHUNK + cg * 4) * (HIN * HIN) + px;
            u16x4 p;
            p.x0 = tob(ip[0]);
            p.x1 = tob(ip[HIN * HIN]);
            p.x2 = tob(ip[2 * HIN * HIN]);
            p.x3 = tob(ip[3 * HIN * HIN]);
            *(u16x4*)&bs[((iy + 2) * HP + ix + 2) * STRIDE + cg * 4] = p;
        }
        __syncthreads();

        // per-m A row base pointers for this ci-chunk
        const u16* Ar[MT];
#pragma unroll
        for (int m = 0; m < MT; ++m)
            Ar[m] = A + ch * CHUNK + quad * 8 + (size_t)(cob + m * 16 + lm) * CIN;

        if constexpr (MT <= 4) {
            // distance-2 pipeline: P computes, Q in flight (and vice versa)
            bf16x8 P0[MT], P1[MT], Q0[MT], Q1[MT];
            MC_LD(P0, 0); MC_LD(P1, 1);
#pragma unroll 1
            for (int it = 0; it < NIT - 2; it += 4) {
                MC_LD(Q0, it + 2); MC_LD(Q1, it + 3);
                MC_FMA(P0, it); MC_FMA(P1, it + 1);
                if (it + 4 < NIT) { MC_LD(P0, it + 4); MC_LD(P1, it + 5); }
                MC_FMA(Q0, it + 2); MC_FMA(Q1, it + 3);
            }
            // NIT % 4 == 2 tail (P0/P1 hold NIT-2, NIT-1)
            MC_FMA(P0, NIT - 2); MC_FMA(P1, NIT - 1);
        } else {
            // distance-1 (verified r5-r8 path) — MT=5 VGPR budget
            bf16x8 af0[MT], af1[MT];
            MC_LD(af0, 0);
#pragma unroll 1
            for (int it = 0; it < NIT; it += 2) {
                MC_LD(af1, it + 1);
                MC_FMA(af0, it);
                if (it + 2 < NIT) MC_LD(af0, it + 2);
                MC_FMA(af1, it + 1);
            }
        }
    }

    if constexpr (O16) {
        __syncthreads();          // all MFMA reads of bs done before reuse
#pragma unroll
        for (int m = 0; m < MT; ++m)
#pragma unroll
            for (int nt = 0; nt < 4; ++nt)
#pragma unroll
                for (int r = 0; r < 4; ++r) {
                    int co = cob + m * 16 + quad * 4 + r;
                    bs[co * 64 + nt * 16 + lm] = f2b(acc[m][nt][r] + bias[co]);
                }
        __syncthreads();
        u16* ob = out + (size_t)b * COUT * 64;
        const unsigned* osw = (const unsigned*)bs;
#pragma unroll
        for (int it = 0; it < COUT / 16; ++it) {
            int v = it * 256 + tid;
            unsigned lo = osw[v * 2], hi = osw[v * 2 + 1];
            *(u64t*)&ob[v * 4] = (u64t)lo | ((u64t)hi << 32);
        }
    } else {
        float* ob = (float*)out + (size_t)b * COUT * 64;
#pragma unroll
        for (int m = 0; m < MT; ++m)
#pragma unroll
            for (int nt = 0; nt < 4; ++nt) {
                int px = nt * 16 + lm;
#pragma unroll
                for (int r = 0; r < 4; ++r) {
                    int co = cob + m * 16 + quad * 4 + r;
                    ob[(size_t)co * 64 + px] = acc[m][nt][r] + bias[co];
                }
            }
    }
}
#undef MC_LD
#undef MC_FMA

// ---------------------------------------------------------------------------
// MFMA GDN, all 4 sites (verified r5). Tile = [256ch][64px] bf16, in place.
// ---------------------------------------------------------------------------
template<bool INVERSE, int IMG, int YOFF, int RS>
__global__ __launch_bounds__(256)
void gdnm(u16* __restrict__ x, const float* __restrict__ beta,
          const u16* __restrict__ Ag)
{
    constexpr int STR = 264;
    __shared__ u16 xb[256 * 64];   // original bf16 tile [ch][px]  (32 KB)
    __shared__ u16 xq[64 * STR];   // bf16 squares [px][ci]        (33 KB)
    const int tid = threadIdx.x;
    const int lane = tid & 63, wv = tid >> 6;
    const int lm = lane & 15, quad = lane >> 4;
    const int cob = wv * 64;
    u16* xg = x + (size_t)blockIdx.x * IMG + (size_t)blockIdx.y * YOFF;

#pragma unroll
    for (int it = 0; it < 16; ++it) {
        int v = it * 256 + tid;          // [0,4096)
        int ch = v >> 4, pxg = (v & 15) * 4;
        *(u64t*)&xb[v * 4] = *(const u64t*)&xg[(size_t)ch * RS + pxg];
    }
    __syncthreads();

    // build xq[px][ci] = bf16(x^2); bank-staggered ((w+px)&31) -> conflict-free
    {
        const int px = tid & 63, g = tid >> 6;   // g in [0,4): 64-ci band
#pragma unroll
        for (int w = 0; w < 32; ++w) {
            int ci = g * 64 + ((w + px) & 31) * 2;
            float x0 = b2f(xb[ci * 64 + px]);
            float x1 = b2f(xb[(ci + 1) * 64 + px]);
            unsigned pk = (unsigned)f2b(x0 * x0) | ((unsigned)f2b(x1 * x1) << 16);
            *(unsigned*)&xq[px * STR + ci] = pk;
        }
    }
    __syncthreads();

    f32x4 acc[4][4];
#pragma unroll
    for (int m = 0; m < 4; ++m)
#pragma unroll
        for (int n = 0; n < 4; ++n) acc[m][n] = (f32x4){0.f, 0.f, 0.f, 0.f};

#pragma unroll 1
    for (int kc = 0; kc < 8; ++kc) {
        bf16x8 bf[4];
#pragma unroll
        for (int nt = 0; nt < 4; ++nt)
            bf[nt] = *(const bf16x8*)&xq[(nt * 16 + lm) * STR + kc * 32 + quad * 8];
        bf16x8 af[4];
#pragma unroll
        for (int m = 0; m < 4; ++m)
            af[m] = *(const bf16x8*)(Ag + (size_t)(cob + m * 16 + lm) * 256 + kc * 32 + quad * 8);
#pragma unroll
        for (int m = 0; m < 4; ++m)
#pragma unroll
            for (int nt = 0; nt < 4; ++nt)
                acc[m][nt] = __builtin_amdgcn_mfma_f32_16x16x32_bf16(af[m], bf[nt], acc[m][nt], 0, 0, 0);
    }

    // epilogue: scale xb in place (each cell owned by exactly one lane)
#pragma unroll
    for (int m = 0; m < 4; ++m)
#pragma unroll
        for (int nt = 0; nt < 4; ++nt)
#pragma unroll
            for (int r = 0; r < 4; ++r) {
                int co = cob + m * 16 + quad * 4 + r;
                int px = nt * 16 + lm;
                float norm = acc[m][nt][r] + beta[co];
                float rr = INVERSE ? sqrtf(norm) : rsqrtf(norm);
                u16* p = &xb[co * 64 + px];
                *p = f2b(b2f(*p) * rr);
            }
    __syncthreads();

#pragma unroll
    for (int it = 0; it < 16; ++it) {
        int v = it * 256 + tid;
        int ch = v >> 4, pxg = (v & 15) * 4;
        *(u64t*)&xg[(size_t)ch * RS + pxg] = *(const u64t*)&xb[v * 4];
    }
}

// ---------------------------------------------------------------------------
// MFMA ConvTranspose2d k=5 s=2, 8x8 -> 16x16, 256->256, input d1 bf16,
// out bf16 QUADRANT-PLANAR d2[b][q][co][sp]. Distance-2 A prefetch.
// ---------------------------------------------------------------------------
#define MD_LD(DST, I) do {                                                     \
    const int _tt = (I) >> 3, _kk = (I) & 7;                                   \
    const int _ty = _tt / W, _tx = _tt % W;                                    \
    const size_t _oo = (size_t)(_ty * 3 + _tx) * 65536 + _kk * 32;             \
    _Pragma("unroll")                                                          \
    for (int _m = 0; _m < 4; ++_m) DST[_m] = *(const bf16x8*)(Ar[_m] + _oo);   \
} while (0)

#define MD_FMA(SRC, I) do {                                                    \
    const int _tt = (I) >> 3, _kk = (I) & 7;                                   \
    const int _ty = _tt / W, _tx = _tt % W;                                    \
    const int _boff = -(_ty * 10 + _tx) * STRIDE + _kk * 32;                   \
    bf16x8 _bf[4];                                                             \
    _Pragma("unroll")                                                          \
    for (int _nt = 0; _nt < 4; ++_nt)                                          \
        _bf[_nt] = *(const bf16x8*)&bs[bofs[_nt] + _boff];                     \
    _Pragma("unroll")                                                          \
    for (int _m = 0; _m < 4; ++_m)                                             \
        _Pragma("unroll")                                                      \
        for (int _nt = 0; _nt < 4; ++_nt)                                      \
            acc[_m][_nt] = __builtin_amdgcn_mfma_f32_16x16x32_bf16(            \
                SRC[_m], _bf[_nt], acc[_m][_nt], 0, 0, 0);                     \
} while (0)

__global__ __launch_bounds__(256)
void mdeconv2(const u16* __restrict__ in, const u16* __restrict__ A2,
              const float* __restrict__ bias, u16* __restrict__ out)
{
    constexpr int STRIDE = 264;
    __shared__ u16 bs[100 * STRIDE];
    __shared__ u16 os[256 * 64];
    const int b = blockIdx.x, tid = threadIdx.x;
    const int lane = tid & 63, wv = tid >> 6, lm = lane & 15, quad = lane >> 4;
    const int cob = wv * 64;
    const u16* inb = in + (size_t)b * 256 * 64;

    unsigned* bz = (unsigned*)bs;
    for (int i = tid; i < 100 * STRIDE / 2; i += 256) bz[i] = 0u;
    __syncthreads();
    for (int i = tid; i < 64 * 64; i += 256) {
        int px = i & 63, cg = i >> 6;
        int iy = px >> 3, ix = px & 7;
        const u16* ip = inb + (size_t)cg * 4 * 64 + px;
        u16x4 p;
        p.x0 = ip[0]; p.x1 = ip[64]; p.x2 = ip[128]; p.x3 = ip[192];
        *(u16x4*)&bs[((iy + 1) * 10 + ix + 1) * STRIDE + cg * 4] = p;
    }
    __syncthreads();

    int bofs[4];
#pragma unroll
    for (int nt = 0; nt < 4; ++nt) {
        int sp = nt * 16 + lm, sy = sp >> 3, sx = sp & 7;
        bofs[nt] = ((sy + 2) * 10 + sx + 2) * STRIDE + quad * 8;
    }

#pragma unroll
    for (int qy = 0; qy < 2; ++qy)
#pragma unroll
        for (int qx = 0; qx < 2; ++qx) {
            const int q = qy * 2 + qx;
            const int W = 3 - qx;                  // compile-time (unrolled)
            const int NT = (3 - qy) * W;
            const int NITq = NT * 8;               // 72/48/48/32 — all %4==0
            f32x4 acc[4][4];
#pragma unroll
            for (int m = 0; m < 4; ++m)
#pragma unroll
                for (int n = 0; n < 4; ++n) acc[m][n] = (f32x4){0.f, 0.f, 0.f, 0.f};

            const u16* Ar[4];
#pragma unroll
            for (int m = 0; m < 4; ++m)
                Ar[m] = A2 + (size_t)(q * 9) * 65536 + quad * 8 + (size_t)(cob + m * 16 + lm) * 256;

            bf16x8 P0[4], P1[4], Q0[4], Q1[4];
            MD_LD(P0, 0); MD_LD(P1, 1);
#pragma unroll 1
            for (int it = 0; it < NITq - 2; it += 4) {
                MD_LD(Q0, it + 2); MD_LD(Q1, it + 3);
                MD_FMA(P0, it); MD_FMA(P1, it + 1);
                if (it + 4 < NITq) { MD_LD(P0, it + 4); MD_LD(P1, it + 5); }
                MD_FMA(Q0, it + 2); MD_FMA(Q1, it + 3);
            }
            // NITq % 4 == 0 -> no tail

            // bounce fragments -> LDS -> contiguous u32-pair -> u64 stores
#pragma unroll
            for (int m = 0; m < 4; ++m)
#pragma unroll
                for (int nt = 0; nt < 4; ++nt)
#pragma unroll
                    for (int r = 0; r < 4; ++r) {
                        int co = cob + m * 16 + quad * 4 + r;
                        os[co * 64 + nt * 16 + lm] = f2b(acc[m][nt][r] + bias[co]);
                    }
            __syncthreads();
            u16* od = out + ((size_t)(b * 4 + q)) * 256 * 64;
            const unsigned* osw = (const unsigned*)os;
#pragma unroll
            for (int it = 0; it < 16; ++it) {
                int v = it * 256 + tid;
                unsigned lo = osw[v * 2], hi = osw[v * 2 + 1];
                *(u64t*)&od[v * 4] = (u64t)lo | ((u64t)hi << 32);
            }
            __syncthreads();
        }
}
#undef MD_LD
#undef MD_FMA

// ---------------------------------------------------------------------------
// deconv3 (VALU): ConvTranspose2d s2, 256->2, 16x16 -> 32x32, clip [0,1].
// Input d2 bf16 QUADRANT-PLANAR [b][q][ci][sp]. f32 dword output stores.
// ---------------------------------------------------------------------------
__global__ __launch_bounds__(256)
void dec3k(const u16* __restrict__ in, const float* __restrict__ W3r,
           const float* __restrict__ bias, float* __restrict__ out)
{
    constexpr int HT = 18;
    __shared__ float ls[32 * HT * HT];
    const int b = blockIdx.x, tid = threadIdx.x;
    const int sy = tid >> 4, sx = tid & 15;
    const u16* inb = in + (size_t)b * 4 * 256 * 64;
    float acc[4][2] = {};
#pragma unroll 1
    for (int ch = 0; ch < 8; ++ch) {
        if (ch) __syncthreads();
        for (int i = tid; i < 32 * HT * HT; i += 256) ls[i] = 0.f;
        __syncthreads();
        for (int i = tid; i < 32 * 256; i += 256) {
            int ci = i >> 8, px = i & 255, iy = px >> 4, ix = px & 15;
            int q = (iy & 1) * 2 + (ix & 1);
            int sp = (iy >> 1) * 8 + (ix >> 1);
            ls[ci * (HT * HT) + (iy + 1) * HT + ix + 1] =
                b2f(inb[((size_t)q * 256 + ch * 32 + ci) * 64 + sp]);
        }
        __syncthreads();
#pragma unroll 1
        for (int ci = 0; ci < 32; ++ci) {
            float v[9];
            const float* l = &ls[ci * (HT * HT) + (sy + 2) * HT + sx + 2];
#pragma unroll
            for (int ty = 0; ty < 3; ++ty)
#pragma unroll
                for (int tx = 0; tx < 3; ++tx) v[ty * 3 + tx] = l[-(ty * HT) - tx];
#pragma unroll
            for (int q = 0; q < 4; ++q) {
                const float* wp = W3r + (size_t)ufl(((q * 256 + ch * 32 + ci) * 2) * 16);
#pragma unroll
                for (int t = 0; t < 9; ++t) {
                    acc[q][0] = fmaf(wp[t], v[t], acc[q][0]);
                    acc[q][1] = fmaf(wp[16 + t], v[t], acc[q][1]);
                }
            }
        }
    }
    float* ob = out + (size_t)b * 2 * 1024;
#pragma unroll
    for (int q = 0; q < 4; ++q) {
        int qy = q >> 1, qx = q & 1;
        int oy = 2 * sy + qy, ox = 2 * sx + qx;
#pragma unroll
        for (int co = 0; co < 2; ++co) {
            float r = acc[q][co] + bias[co];
            r = fminf(fmaxf(r, 0.f), 1.f);
            ob[(size_t)co * 1024 + oy * 32 + ox] = r;
        }
    }
}

// ---------------------------------------------------------------------------
// conv1: direct conv (CIN=2). bf16 output bounced through LDS -> u32-pair ->
// u64 stores. Only instantiated with PX==256, NCOG==1.
// ---------------------------------------------------------------------------
template<int CIN, int COUT, int HIN, int WIN, int S, int CI_CHUNK, int CO_PER_BLOCK>
__global__ __launch_bounds__(256)
void conv5k(const float* __restrict__ in, const float* __restrict__ wt,
            const float* __restrict__ bias, u16* __restrict__ out)
{
    constexpr int HOUT = HIN / S, WOUT = WIN / S;
    constexpr int PX = HOUT * WOUT;          // 256
    constexpr int CO_ITERS = CO_PER_BLOCK;   // 16
    constexpr int HT = HIN + 4, WT = WIN + 4;
    constexpr int NCHUNK = CIN / CI_CHUNK;
    constexpr int TILE = CI_CHUNK * HT * WT;

    __shared__ float lds[TILE];
    __shared__ u16 os[CO_PER_BLOCK * PX];

    const int b = blockIdx.x;
    const int co_base = blockIdx.y * CO_PER_BLOCK;
    const int tid = threadIdx.x;
    const int px = tid;
    const int oy = px / WOUT, ox = px % WOUT;

    float acc[CO_ITERS];
#pragma unroll
    for (int i = 0; i < CO_ITERS; ++i) acc[i] = 0.f;

    const float* inb = in + (size_t)b * CIN * HIN * WIN;

#pragma unroll 1
    for (int ch = 0; ch < NCHUNK; ++ch) {
        if (ch) __syncthreads();
        for (int idx = tid; idx < TILE; idx += 256) lds[idx] = 0.f;
        __syncthreads();
        for (int idx = tid; idx < CI_CHUNK * HIN * WIN; idx += 256) {
            int ci = idx / (HIN * WIN);
            int r = idx - ci * (HIN * WIN);
            int iy = r / WIN, ix = r - iy * WIN;
            lds[ci * (HT * WT) + (iy + 2) * WT + (ix + 2)] =
                inb[(size_t)(ch * CI_CHUNK + ci) * (HIN * WIN) + r];
        }
        __syncthreads();

#pragma unroll 1
        for (int ci = 0; ci < CI_CHUNK; ++ci) {
            float v[25];
            const float* l = &lds[ci * (HT * WT) + (oy * S) * WT + (ox * S)];
#pragma unroll
            for (int ky = 0; ky < 5; ++ky)
#pragma unroll
                for (int kx = 0; kx < 5; ++kx)
                    v[ky * 5 + kx] = l[ky * WT + kx];
#pragma unroll
            for (int i = 0; i < CO_ITERS; ++i) {
                const int co = co_base + i;
                const float* wp = wt + (size_t)ufl((co * CIN + ch * CI_CHUNK + ci) * 25);
#pragma unroll
                for (int t = 0; t < 25; ++t) acc[i] = fmaf(wp[t], v[t], acc[i]);
            }
        }
    }

#pragma unroll
    for (int i = 0; i < CO_ITERS; ++i)
        os[i * PX + px] = f2b(acc[i] + bias[co_base + i]);
    __syncthreads();
    u16* ob = out + ((size_t)b * COUT + co_base) * PX;
    const unsigned* osw = (const unsigned*)os;
#pragma unroll
    for (int it = 0; it < CO_PER_BLOCK * PX / 1024; ++it) {
        int v = it * 256 + tid;
        unsigned lo = osw[v * 2], hi = osw[v * 2 + 1];
        *(u64t*)&ob[v * 4] = (u64t)lo | ((u64t)hi << 32);
    }
}

// ---------------------------------------------------------------------------
// Batched context model (verified r8): GEMM1 -> w_hat/lik -> GEMM2.
// ---------------------------------------------------------------------------
__global__ __launch_bounds__(256)
void trik_m(float* __restrict__ y, const float* __restrict__ noise,
            const u16* __restrict__ Hb, const u16* __restrict__ Mb,
            const float* __restrict__ mean, const float* __restrict__ scale,
            float* __restrict__ lik)
{
    __shared__ float Ysf[64 * 68];   // f32 y tile [b][i]
    __shared__ u16 Yt[64 * 72];      // bf16 B operand [b][k]; reused for W_hat
    const int c = blockIdx.x;
    const int b0 = blockIdx.y * 64;
    const int tid = threadIdx.x;
    const int lane = tid & 63, wv = tid >> 6;
    const int lm = lane & 15, quad = lane >> 4;
    const int cob = wv * 16;

    // stage y -> Ysf (f32) + Yt (bf16)
#pragma unroll
    for (int it = 0; it < 4; ++it) {
        int v = it * 256 + tid;            // [0,1024)
        int b = v >> 4, i0 = (v & 15) * 4;
        f32x4 t = *(const f32x4*)(y + (size_t)(b0 + b) * 20480 + c * 64 + i0);
        *(f32x4*)&Ysf[b * 68 + i0] = t;
        u16x4 p;
        p.x0 = f2b(t[0]); p.x1 = f2b(t[1]); p.x2 = f2b(t[2]); p.x3 = f2b(t[3]);
        *(u16x4*)&Yt[b * 72 + i0] = p;
    }
    __syncthreads();

    // GEMM1: C[i][b] = sum_k H_tril[i][k] * Y[k][b]
    f32x4 acc[4];
#pragma unroll
    for (int nt = 0; nt < 4; ++nt) acc[nt] = (f32x4){0.f, 0.f, 0.f, 0.f};
    const u16* Ha = Hb + (size_t)c * 4096 + (cob + lm) * 64 + quad * 8;
#pragma unroll
    for (int kc = 0; kc < 2; ++kc) {
        bf16x8 af = *(const bf16x8*)(Ha + kc * 32);
#pragma unroll
        for (int nt = 0; nt < 4; ++nt) {
            bf16x8 bf = *(const bf16x8*)&Yt[(nt * 16 + lm) * 72 + kc * 32 + quad * 8];
            acc[nt] = __builtin_amdgcn_mfma_f32_16x16x32_bf16(af, bf, acc[nt], 0, 0, 0);
        }
    }
    __syncthreads();   // all GEMM1 reads of Yt complete before overwrite

    // w_hat (f32, kept in regs) + lik; write bf16 W_hat into Yt
    const int i0 = cob + quad * 4;
    const f32x4 mn4 = *(const f32x4*)(mean + c * 64 + i0);
    const f32x4 sc4 = *(const f32x4*)(scale + c * 64 + i0);
    float whf[4][4];
#pragma unroll
    for (int nt = 0; nt < 4; ++nt) {
        int b = nt * 16 + lm;
        f32x4 nz = *(const f32x4*)(noise + (size_t)(b0 + b) * 20480 + c * 64 + i0);
        f32x4 lk;
#pragma unroll
        for (int r = 0; r < 4; ++r) {
            float wh = Ysf[b * 68 + i0 + r] - acc[nt][r] + nz[r];
            whf[nt][r] = wh;
            const float sc = fmaxf(sc4[r], 0.11f);
            const float vv = fabsf(wh - mn4[r]);
            const float cst = -0.70710678118654752f;
            const float upper = 0.5f * erfcf(cst * (0.5f - vv) / sc);
            const float lower = 0.5f * erfcf(cst * (-0.5f - vv) / sc);
            lk[r] = fmaxf(upper - lower, 1e-9f);
        }
        *(f32x4*)(lik + (size_t)(b0 + b) * 20480 + c * 64 + i0) = lk;
        u16x4 p;
        p.x0 = f2b(whf[nt][0]); p.x1 = f2b(whf[nt][1]);
        p.x2 = f2b(whf[nt][2]); p.x3 = f2b(whf[nt][3]);
        *(u16x4*)&Yt[b * 72 + i0] = p;
    }
    __syncthreads();

    // GEMM2: y_hat = w_hat + (Minv - I) @ W_hat
    f32x4 acc2[4];
#pragma unroll
    for (int nt = 0; nt < 4; ++nt) acc2[nt] = (f32x4){0.f, 0.f, 0.f, 0.f};
    const u16* Ma = Mb + (size_t)c * 4096 + (cob + lm) * 64 + quad * 8;
#pragma unroll
    for (int kc = 0; kc < 2; ++kc) {
        bf16x8 af = *(const bf16x8*)(Ma + kc * 32);
#pragma unroll
        for (int nt = 0; nt < 4; ++nt) {
            bf16x8 bf = *(const bf16x8*)&Yt[(nt * 16 + lm) * 72 + kc * 32 + quad * 8];
            acc2[nt] = __builtin_amdgcn_mfma_f32_16x16x32_bf16(af, bf, acc2[nt], 0, 0, 0);
        }
    }
#pragma unroll
    for (int nt = 0; nt < 4; ++nt) {
        int b = nt * 16 + lm;
        f32x4 yh;
#pragma unroll
        for (int r = 0; r < 4; ++r) yh[r] = whf[nt][r] + acc2[nt][r];
        *(f32x4*)(y + (size_t)(b0 + b) * 20480 + c * 64 + i0) = yh;
    }
}

// ---------------------------------------------------------------------------
extern "C" void kernel_launch(void* const* d_in, const int* in_sizes, int n_in,
                              void* d_out, int out_size, void* d_ws, size_t ws_size,
                              hipStream_t stream)
{
    (void)in_sizes; (void)n_in; (void)out_size; (void)ws_size;

    const float* x      = (const float*)d_in[0];
    const float* noise  = (const float*)d_in[1];
    const float* w1     = (const float*)d_in[2];
    const float* b1     = (const float*)d_in[3];
    const float* beta1  = (const float*)d_in[4];
    const float* gamma1 = (const float*)d_in[5];
    const float* w2     = (const float*)d_in[6];
    const float* b2     = (const float*)d_in[7];
    const float* beta2  = (const float*)d_in[8];
    const float* gamma2 = (const float*)d_in[9];
    const float* w3     = (const float*)d_in[10];
    const float* b3     = (const float*)d_in[11];
    const float* dw1    = (const float*)d_in[12];
    const float* db1    = (const float*)d_in[13];
    const float* ibeta1 = (const float*)d_in[14];
    const float* igamma1= (const float*)d_in[15];
    const float* dw2    = (const float*)d_in[16];
    const float* db2    = (const float*)d_in[17];
    const float* ibeta2 = (const float*)d_in[18];
    const float* igamma2= (const float*)d_in[19];
    const float* dw3    = (const float*)d_in[20];
    const float* db3    = (const float*)d_in[21];
    const float* mean   = (const float*)d_in[22];
    const float* scale  = (const float*)d_in[23];
    const float* H      = (const float*)d_in[24];

    float* outp = (float*)d_out;
    float* xhat = outp;                                   // [1024,2,32,32]
    float* lik  = outp + (size_t)1024 * 2 * 32 * 32;      // [1024,320,64]

    // workspace layout:
    //   [0, 134.2M)        a1 bf16 -> y f32 -> d2 bf16 (quadrant-planar)
    //   [134.2M, 167.8M)   a2 bf16 -> d1 bf16  (33.5 MB)
    //   [167.8M, 168.3M)   repacked gammas (4 x 128 KB)
    //   [168.3M, 173.6M)   Hb, Mb (context bf16 mats, 2 x 2.62 MB)
    //   [201.3M, 217.8M)   repacked conv weights
    char* ws = (char*)d_ws;
    u16*   a1  = (u16*)ws;
    float* y   = (float*)ws;
    u16*   d2  = (u16*)ws;
    u16*   a2  = (u16*)(ws + 134217728);
    u16*   d1  = (u16*)(ws + 134217728);
    u16*   Ag1 = (u16*)(ws + 167772160);
    u16*   Ag2 = (u16*)(ws + 167903232);
    u16*   Ag3 = (u16*)(ws + 168034304);
    u16*   Ag4 = (u16*)(ws + 168165376);
    u16*   Hb  = (u16*)(ws + 168296448);
    u16*   Mb  = (u16*)(ws + 170917888);
    u16*   Ac2 = (u16*)(ws + 201326592);
    u16*   Ac3 = (u16*)(ws + 204603392);
    u16*   Ad1 = (u16*)(ws + 208699392);
    u16*   Ad2 = (u16*)(ws + 212795392);
    float* W3r = (float*)(ws + 217513984);

    // ---- weight repacks ----
    rk_fwd<256, 256><<<3200, 256, 0, stream>>>(w2, Ac2);
    rk_fwd<256, 320><<<4000, 256, 0, stream>>>(w3, Ac3);
    rk_d1<<<4000, 256, 0, stream>>>(dw1, Ad1);
    rk_d2<<<4608, 256, 0, stream>>>(dw2, Ad2);
    rk_d3<<<128, 256, 0, stream>>>(dw3, W3r);
    rk_g<<<128, 256, 0, stream>>>(gamma1, Ag1);
    rk_g<<<128, 256, 0, stream>>>(gamma2, Ag2);
    rk_g<<<128, 256, 0, stream>>>(igamma1, Ag3);
    rk_g<<<128, 256, 0, stream>>>(igamma2, Ag4);
    rk_hb<<<2560, 256, 0, stream>>>(H, Hb);
    rk_inv<<<320, 256, 0, stream>>>(H, Mb);

    // ---- analysis ----
    conv5k<2, 256, 32, 32, 2, 2, 16><<<dim3(1024, 16), 256, 0, stream>>>(x, w1, b1, a1);
    gdnm<false, 65536, 64, 256><<<dim3(1024, 4), 256, 0, stream>>>(a1, beta1, Ag1);
    mconv<256, 256, 2, 4, u16, u16><<<1024, 256, 0, stream>>>(a1, Ac2, b2, a2);
    gdnm<false, 16384, 16384, 64><<<dim3(1024, 1), 256, 0, stream>>>(a2, beta2, Ag2);
    mconv<256, 320, 1, 5, u16, float><<<1024, 256, 0, stream>>>(a2, Ac3, b3, y);

    // ---- context model (batched MFMA form) ----
    trik_m<<<dim3(320, 16), 256, 0, stream>>>(y, noise, Hb, Mb, mean, scale, lik);

    // ---- synthesis ----
    mconv<320, 256, 1, 4, float, u16><<<1024, 256, 0, stream>>>(y, Ad1, db1, d1);
    gdnm<true, 16384, 16384, 64><<<dim3(1024, 1), 256, 0, stream>>>(d1, ibeta1, Ag3);
    mdeconv2<<<1024, 256, 0, stream>>>(d1, Ad2, db2, d2);
    gdnm<true, 65536, 16384, 64><<<dim3(1024, 4), 256, 0, stream>>>(d2, ibeta2, Ag4);
    dec3k<<<1024, 256, 0, stream>>>(d2, W3r, db3, xhat);
}